// Round 11
// baseline (26.780 us; speedup 1.0000x reference)
//
#include <hip/hip_runtime.h>
#include <math.h>

// B=2, N=512, DIM=3, C_IN=64, C_OUT=64
// ws layout (floats): s[1024] | gm4[1024*256]
#define WS_S   0
#define WS_GM4 1024

static __device__ __forceinline__ float rlf(float v, int l) {
    return __builtin_bit_cast(float,
        __builtin_amdgcn_readlane(__builtin_bit_cast(int, v), l));
}

// ---------------------------------------------------------------------------
// Prep, grid 512 x 256 (R9-proven):
//  all bx:  zero out[bx*384 .. +384)
//  bx<256:  4 bj each:  s[bj] = sum_c ||geom[bj,:,c]||*norm_w[c] + norm_b
//           gm4[bj][co] = {geom[bj,:,:] @ theta[:64,co], 0}   (float4)
// ---------------------------------------------------------------------------
__global__ __launch_bounds__(256) void prep_kernel(
    const float* __restrict__ geom,    // [1024,3,64]
    const float* __restrict__ theta,   // [65,64]
    const float* __restrict__ norm_w,  // [65]
    const float* __restrict__ norm_b,  // [1]
    float* __restrict__ s,             // [1024]
    float* __restrict__ gm4,           // [1024,64,4]
    float* __restrict__ out)           // [1024,192]
{
    const int bx  = blockIdx.x;
    const int tid = threadIdx.x;

    for (int k = tid; k < 384; k += 256)
        out[(size_t)bx * 384 + k] = 0.f;

    if (bx < 256) {
        const int sub  = tid >> 6;      // which of 4 bj
        const int lane = tid & 63;      // = c, and = co
        const int bj   = bx * 4 + sub;
        __shared__ float g[4][192];     // [d*64 + c]
        const float* gb = geom + (size_t)bj * 192;
        g[sub][lane]       = gb[lane];
        g[sub][lane + 64]  = gb[lane + 64];
        g[sub][lane + 128] = gb[lane + 128];
        __syncthreads();

        {
            float g0 = g[sub][lane], g1 = g[sub][64 + lane], g2 = g[sub][128 + lane];
            float t = sqrtf(g0 * g0 + g1 * g1 + g2 * g2) * norm_w[lane];
            for (int off = 32; off > 0; off >>= 1) t += __shfl_down(t, off);
            if (lane == 0) s[bj] = t + norm_b[0];
        }

        float a0 = 0.f, a1 = 0.f, a2 = 0.f;
        for (int c = 0; c < 64; ++c) {
            float th = theta[c * 64 + lane];
            a0 = fmaf(g[sub][c],       th, a0);
            a1 = fmaf(g[sub][64 + c],  th, a1);
            a2 = fmaf(g[sub][128 + c], th, a2);
        }
        *reinterpret_cast<float4*>(gm4 + (size_t)bj * 256 + lane * 4) =
            make_float4(a0, a1, a2, 0.f);
    }
}

// ---------------------------------------------------------------------------
// Main, grid 512 = (b*256 + iq*2 + jh), 512 thr = 8 waves (16 waves/CU).
// Block = (b, i-quad, j-half). Wave = 32-j chunk x 4 i; lane = co in consume.
// Per-pair operands live in REGISTERS (pack phase: lane = pair slot;
// round A = il{0,1}, round B = il{2,3}; 5 f32 payload each) and are
// broadcast via v_readlane -> SGPR (<=1 SGPR per consuming VALU op).
// NO LDS in the main loop (R9 was bound by 2048 broadcast ds_read_b128/CU
// = 24.6K cyc = 10.2us on the LDS pipe). gm via coalesced dwordx4/jj
// reused x4. Epilogue: 8-wave LDS reduce + 2-way atomicAdd into
// prep-zeroed out (2 commutative addends -> deterministic).
//   an = adj*naf;  w = max(al*an + be*adj, 0);  acc_d += w*(gm_d + r_d*t64)
// ---------------------------------------------------------------------------
__global__ __launch_bounds__(512) void main_kernel(
    const float* __restrict__ adj,     // [1024,512]
    const float* __restrict__ rel,     // [1024,512,3]
    const float* __restrict__ emb,     // [1024,512]
    const float* __restrict__ s_arr,   // [1024]
    const float* __restrict__ gm4,     // [1024,64,4]
    const float* __restrict__ theta,   // [65,64]
    const float* __restrict__ norm_w,  // [65]
    const float* __restrict__ alpha,   // [64]
    const float* __restrict__ beta,    // [64]
    float* __restrict__ out)           // [1024,192]
{
    const int bx   = blockIdx.x;
    const int jh   = bx & 1;
    const int iq   = (bx >> 1) & 127;
    const int b    = bx >> 8;
    const int tid  = threadIdx.x;      // 0..511
    const int lane = tid & 63;
    const int wv   = tid >> 6;         // 0..7
    const int bi0  = b * 512 + iq * 4;
    const int j0   = jh * 256;

    // ---- pack this wave's 128 pairs into registers ----
    // lane slot: il_off = lane>>5 (0/1), j = wv*32 + (lane&31)
    const int il_off = lane >> 5;
    const int jp     = j0 + wv * 32 + (lane & 31);
    const float nw64 = norm_w[64];
    const float sj   = s_arr[b * 512 + jp];

    float anA, avA, r0A, r1A, r2A;
    float anB, avB, r0B, r1B, r2B;
    {
        size_t p = (size_t)(bi0 + il_off) * 512 + jp;
        r0A = rel[p * 3]; r1A = rel[p * 3 + 1]; r2A = rel[p * 3 + 2];
        avA = adj[p];
        float e2 = fmaf(nw64, sqrtf(r0A * r0A + r1A * r1A + r2A * r2A), emb[p]);
        anA = avA * (sj + e2);
    }
    {
        size_t p = (size_t)(bi0 + il_off + 2) * 512 + jp;
        r0B = rel[p * 3]; r1B = rel[p * 3 + 1]; r2B = rel[p * 3 + 2];
        avB = adj[p];
        float e2 = fmaf(nw64, sqrtf(r0B * r0B + r1B * r1B + r2B * r2B), emb[p]);
        anB = avB * (sj + e2);
    }

    const float al  = alpha[lane];
    const float be  = beta[lane];
    const float t64 = theta[64 * 64 + lane];

    const float4* gmv =
        (const float4*)gm4 + ((size_t)(b * 512 + j0 + wv * 32)) * 64 + lane;

    float acc[4][3];
    #pragma unroll
    for (int il = 0; il < 4; ++il)
        acc[il][0] = acc[il][1] = acc[il][2] = 0.f;

#define PAIR(AN, AV, R0, R1, R2, IDX, A0, A1, A2)                          \
    {                                                                      \
        float an = rlf(AN, IDX), av = rlf(AV, IDX);                        \
        float r0 = rlf(R0, IDX), r1 = rlf(R1, IDX), r2 = rlf(R2, IDX);     \
        float w  = fmaxf(fmaf(al, an, be * av), 0.f);                      \
        A0 = fmaf(w, fmaf(r0, t64, g.x), A0);                              \
        A1 = fmaf(w, fmaf(r1, t64, g.y), A1);                              \
        A2 = fmaf(w, fmaf(r2, t64, g.z), A2);                              \
    }

    #pragma unroll
    for (int jj = 0; jj < 32; ++jj) {
        float4 g = gmv[(size_t)jj * 64];
        PAIR(anA, avA, r0A, r1A, r2A, jj,      acc[0][0], acc[0][1], acc[0][2]);
        PAIR(anA, avA, r0A, r1A, r2A, 32 + jj, acc[1][0], acc[1][1], acc[1][2]);
        PAIR(anB, avB, r0B, r1B, r2B, jj,      acc[2][0], acc[2][1], acc[2][2]);
        PAIR(anB, avB, r0B, r1B, r2B, 32 + jj, acc[3][0], acc[3][1], acc[3][2]);
    }
#undef PAIR

    // ---- 8-wave LDS reduce (lane-contiguous b32, conflict-free) ----
    __shared__ float red[8][768];
    float* rw = &red[wv][lane];
    #pragma unroll
    for (int il = 0; il < 4; ++il) {
        rw[il * 192]       = acc[il][0];
        rw[il * 192 + 64]  = acc[il][1];
        rw[il * 192 + 128] = acc[il][2];
    }
    __syncthreads();

    for (int k = tid; k < 768; k += 512) {
        float v = 0.f;
        #pragma unroll
        for (int w8 = 0; w8 < 8; ++w8) v += red[w8][k];
        int il = k / 192, r = k - il * 192;
        atomicAdd(&out[(size_t)(bi0 + il) * 192 + r], v);
    }
}

extern "C" void kernel_launch(void* const* d_in, const int* in_sizes, int n_in,
                              void* d_out, int out_size, void* d_ws, size_t ws_size,
                              hipStream_t stream) {
    const float* geom   = (const float*)d_in[0];
    const float* adj    = (const float*)d_in[1];
    const float* rel    = (const float*)d_in[2];
    const float* emb    = (const float*)d_in[3];
    const float* theta  = (const float*)d_in[4];
    const float* norm_w = (const float*)d_in[5];
    const float* norm_b = (const float*)d_in[6];
    const float* alpha  = (const float*)d_in[7];
    const float* beta   = (const float*)d_in[8];
    float* out = (float*)d_out;

    float* ws  = (float*)d_ws;
    float* s   = ws + WS_S;
    float* gm4 = ws + WS_GM4;

    prep_kernel<<<512, 256, 0, stream>>>(geom, theta, norm_w, norm_b, s, gm4, out);
    main_kernel<<<512, 512, 0, stream>>>(adj, rel, emb, s, gm4, theta, norm_w,
                                         alpha, beta, out);
}

// Round 13
// 26.013 us; speedup vs baseline: 1.0295x; 1.0295x over previous
//
#include <hip/hip_runtime.h>
#include <math.h>

// B=2, N=512, DIM=3, C_IN=64, C_OUT=64
// ws layout (floats): s[1024] | gm4[1024*256]
#define WS_S   0
#define WS_GM4 1024

typedef unsigned int u32;

static __device__ __forceinline__ u32 bf16b(float x) {
    u32 u = __builtin_bit_cast(u32, x);
    return (u + 0x7FFFu + ((u >> 16) & 1u)) >> 16;   // RNE to bf16
}
static __device__ __forceinline__ float blo(u32 b) {   // low bf16 -> f32
    return __builtin_bit_cast(float, b << 16);
}
static __device__ __forceinline__ float bhi(u32 b) {   // high bf16 -> f32
    return __builtin_bit_cast(float, b & 0xFFFF0000u);
}

// ---------------------------------------------------------------------------
// Prep, grid 512 x 256 (R9-proven):
//  all bx:  zero out[bx*384 .. +384)
//  bx<256:  4 bj each:  s[bj] = sum_c ||geom[bj,:,c]||*norm_w[c] + norm_b
//           gm4[bj][co] = {geom[bj,:,:] @ theta[:64,co], 0}   (float4)
// ---------------------------------------------------------------------------
__global__ __launch_bounds__(256) void prep_kernel(
    const float* __restrict__ geom,    // [1024,3,64]
    const float* __restrict__ theta,   // [65,64]
    const float* __restrict__ norm_w,  // [65]
    const float* __restrict__ norm_b,  // [1]
    float* __restrict__ s,             // [1024]
    float* __restrict__ gm4,           // [1024,64,4]
    float* __restrict__ out)           // [1024,192]
{
    const int bx  = blockIdx.x;
    const int tid = threadIdx.x;

    for (int k = tid; k < 384; k += 256)
        out[(size_t)bx * 384 + k] = 0.f;

    if (bx < 256) {
        const int sub  = tid >> 6;      // which of 4 bj
        const int lane = tid & 63;      // = c, and = co
        const int bj   = bx * 4 + sub;
        __shared__ float g[4][192];     // [d*64 + c]
        const float* gb = geom + (size_t)bj * 192;
        g[sub][lane]       = gb[lane];
        g[sub][lane + 64]  = gb[lane + 64];
        g[sub][lane + 128] = gb[lane + 128];
        __syncthreads();

        {
            float g0 = g[sub][lane], g1 = g[sub][64 + lane], g2 = g[sub][128 + lane];
            float t = sqrtf(g0 * g0 + g1 * g1 + g2 * g2) * norm_w[lane];
            for (int off = 32; off > 0; off >>= 1) t += __shfl_down(t, off);
            if (lane == 0) s[bj] = t + norm_b[0];
        }

        float a0 = 0.f, a1 = 0.f, a2 = 0.f;
        for (int c = 0; c < 64; ++c) {
            float th = theta[c * 64 + lane];
            a0 = fmaf(g[sub][c],       th, a0);
            a1 = fmaf(g[sub][64 + c],  th, a1);
            a2 = fmaf(g[sub][128 + c], th, a2);
        }
        *reinterpret_cast<float4*>(gm4 + (size_t)bj * 256 + lane * 4) =
            make_float4(a0, a1, a2, 0.f);
    }
}

// ---------------------------------------------------------------------------
// Main, grid 512 = (b*256 + iq*2 + jh), 512 thr = 8 waves (16 waves/CU).
// R9 structure; payload compressed 16B -> 8B/pair (bf16 naf,av,r0,r1) plus
// a shared r2-plane (4 x bf16 = 8B per jj). Consume per jj: 2x ds_read_b128
// + 1x ds_read_b64 (~31 cyc) instead of R9's 4x b128 (~48 cyc) -> LDS pipe
// 10.2 -> ~6.6 us/CU, VALU ~5.8 us/CU, balanced.
//   t = max(fmaf(al,naf,be),0);  w = av*t;  acc_d += w*(gm_d + r_d*t64)
// Epilogue: 8-wave LDS reduce + 2-way atomicAdd into prep-zeroed out.
// ---------------------------------------------------------------------------
__global__ __launch_bounds__(512) void main_kernel(
    const float* __restrict__ adj,     // [1024,512]
    const float* __restrict__ rel,     // [1024,512,3]
    const float* __restrict__ emb,     // [1024,512]
    const float* __restrict__ s_arr,   // [1024]
    const float* __restrict__ gm4,     // [1024,64,4]
    const float* __restrict__ theta,   // [65,64]
    const float* __restrict__ norm_w,  // [65]
    const float* __restrict__ alpha,   // [64]
    const float* __restrict__ beta,    // [64]
    float* __restrict__ out)           // [1024,192]
{
    const int bx   = blockIdx.x;
    const int jh   = bx & 1;
    const int iq   = (bx >> 1) & 127;
    const int b    = bx >> 8;
    const int tid  = threadIdx.x;      // 0..511
    const int lane = tid & 63;         // co
    const int wv   = tid >> 6;         // 0..7
    const int bi0  = b * 512 + iq * 4;
    const int j0   = jh * 256;

    __shared__ uint4 pk8q_l[256][2];   // 8 KB: [j][{il01,il23}]
    __shared__ uint2 r2p_l[256];       // 2 KB: [j] = 4x bf16 r2
    __shared__ float red[8][768];      // 24 KB

    // ---- pack: thread t=(il,j) builds its 8B pair + 2B r2 slot ----
    {
        const float nw64 = norm_w[64];
        #pragma unroll
        for (int u = 0; u < 2; ++u) {
            int t  = tid + u * 512;        // 0..1023
            int il = t >> 8;               // 0..3
            int j  = t & 255;
            size_t p = (size_t)(bi0 + il) * 512 + j0 + j;
            const float* rp = rel + p * 3;
            float r0 = rp[0], r1 = rp[1], r2 = rp[2];
            float a   = adj[p];
            float naf = s_arr[b * 512 + j0 + j]
                      + nw64 * sqrtf(r0 * r0 + r1 * r1 + r2 * r2) + emb[p];
            uint2 q;
            q.x = bf16b(naf) | (bf16b(a) << 16);
            q.y = bf16b(r0)  | (bf16b(r1) << 16);
            *reinterpret_cast<uint2*>(
                reinterpret_cast<char*>(&pk8q_l[j][il >> 1]) + (il & 1) * 8) = q;
            reinterpret_cast<unsigned short*>(r2p_l)[j * 4 + il] =
                (unsigned short)bf16b(r2);
        }
    }
    __syncthreads();

    const float al  = alpha[lane];
    const float be  = beta[lane];
    const float t64 = theta[64 * 64 + lane];

    const float4* gmv =
        (const float4*)gm4 + ((size_t)(b * 512 + j0 + wv * 32)) * 64 + lane;

    float acc[4][3];
    #pragma unroll
    for (int il = 0; il < 4; ++il)
        acc[il][0] = acc[il][1] = acc[il][2] = 0.f;

#define PAIR(NAFAV, R01, R2V, A0, A1, A2)                                  \
    {                                                                      \
        float naf = blo(NAFAV), av = bhi(NAFAV);                           \
        float r0  = blo(R01),   r1 = bhi(R01);                             \
        float w   = av * fmaxf(fmaf(al, naf, be), 0.f);                    \
        A0 = fmaf(w, fmaf(r0, t64, g.x),  A0);                             \
        A1 = fmaf(w, fmaf(r1, t64, g.y),  A1);                             \
        A2 = fmaf(w, fmaf(R2V, t64, g.z), A2);                             \
    }

    #pragma unroll 4
    for (int jj = 0; jj < 32; ++jj) {
        const int J = wv * 32 + jj;
        float4 g  = gmv[(size_t)jj * 64];
        uint4 qA = pk8q_l[J][0];           // il0, il1 (broadcast b128)
        uint4 qB = pk8q_l[J][1];           // il2, il3
        uint2 rp = r2p_l[J];               // broadcast b64
        PAIR(qA.x, qA.y, blo(rp.x), acc[0][0], acc[0][1], acc[0][2]);
        PAIR(qA.z, qA.w, bhi(rp.x), acc[1][0], acc[1][1], acc[1][2]);
        PAIR(qB.x, qB.y, blo(rp.y), acc[2][0], acc[2][1], acc[2][2]);
        PAIR(qB.z, qB.w, bhi(rp.y), acc[3][0], acc[3][1], acc[3][2]);
    }
#undef PAIR

    // ---- 8-wave LDS reduce (lane-contiguous b32, conflict-free) ----
    float* rw = &red[wv][lane];
    #pragma unroll
    for (int il = 0; il < 4; ++il) {
        rw[il * 192]       = acc[il][0];
        rw[il * 192 + 64]  = acc[il][1];
        rw[il * 192 + 128] = acc[il][2];
    }
    __syncthreads();

    for (int k = tid; k < 768; k += 512) {
        float v = 0.f;
        #pragma unroll
        for (int w8 = 0; w8 < 8; ++w8) v += red[w8][k];
        int il = k / 192, r = k - il * 192;
        atomicAdd(&out[(size_t)(bi0 + il) * 192 + r], v);
    }
}

extern "C" void kernel_launch(void* const* d_in, const int* in_sizes, int n_in,
                              void* d_out, int out_size, void* d_ws, size_t ws_size,
                              hipStream_t stream) {
    const float* geom   = (const float*)d_in[0];
    const float* adj    = (const float*)d_in[1];
    const float* rel    = (const float*)d_in[2];
    const float* emb    = (const float*)d_in[3];
    const float* theta  = (const float*)d_in[4];
    const float* norm_w = (const float*)d_in[5];
    const float* norm_b = (const float*)d_in[6];
    const float* alpha  = (const float*)d_in[7];
    const float* beta   = (const float*)d_in[8];
    float* out = (float*)d_out;

    float* ws  = (float*)d_ws;
    float* s   = ws + WS_S;
    float* gm4 = ws + WS_GM4;

    prep_kernel<<<512, 256, 0, stream>>>(geom, theta, norm_w, norm_b, s, gm4, out);
    main_kernel<<<512, 512, 0, stream>>>(adj, rel, emb, s, gm4, theta, norm_w,
                                         alpha, beta, out);
}

// Round 14
// 24.104 us; speedup vs baseline: 1.1110x; 1.0792x over previous
//
#include <hip/hip_runtime.h>
#include <math.h>

// B=2, N=512, DIM=3, C_IN=64, C_OUT=64
// ws layout (floats): s[1024] | gm4[1024*256]
#define WS_S   0
#define WS_GM4 1024

typedef unsigned int u32;

static __device__ __forceinline__ u32 bf16b(float x) {
    u32 u = __builtin_bit_cast(u32, x);
    return (u + 0x7FFFu + ((u >> 16) & 1u)) >> 16;   // RNE to bf16
}

// ---------------------------------------------------------------------------
// Prep, grid 512 x 256 (R9-proven, unchanged):
//  all bx:  zero out[bx*384 .. +384)
//  bx<256:  4 bj each:  s[bj] = sum_c ||geom[bj,:,c]||*norm_w[c] + norm_b
//           gm4[bj][co] = {geom[bj,:,:] @ theta[:64,co], 0}   (float4)
// ---------------------------------------------------------------------------
__global__ __launch_bounds__(256) void prep_kernel(
    const float* __restrict__ geom,    // [1024,3,64]
    const float* __restrict__ theta,   // [65,64]
    const float* __restrict__ norm_w,  // [65]
    const float* __restrict__ norm_b,  // [1]
    float* __restrict__ s,             // [1024]
    float* __restrict__ gm4,           // [1024,64,4]
    float* __restrict__ out)           // [1024,192]
{
    const int bx  = blockIdx.x;
    const int tid = threadIdx.x;

    for (int k = tid; k < 384; k += 256)
        out[(size_t)bx * 384 + k] = 0.f;

    if (bx < 256) {
        const int sub  = tid >> 6;      // which of 4 bj
        const int lane = tid & 63;      // = c, and = co
        const int bj   = bx * 4 + sub;
        __shared__ float g[4][192];     // [d*64 + c]
        const float* gb = geom + (size_t)bj * 192;
        g[sub][lane]       = gb[lane];
        g[sub][lane + 64]  = gb[lane + 64];
        g[sub][lane + 128] = gb[lane + 128];
        __syncthreads();

        {
            float g0 = g[sub][lane], g1 = g[sub][64 + lane], g2 = g[sub][128 + lane];
            float t = sqrtf(g0 * g0 + g1 * g1 + g2 * g2) * norm_w[lane];
            for (int off = 32; off > 0; off >>= 1) t += __shfl_down(t, off);
            if (lane == 0) s[bj] = t + norm_b[0];
        }

        float a0 = 0.f, a1 = 0.f, a2 = 0.f;
        for (int c = 0; c < 64; ++c) {
            float th = theta[c * 64 + lane];
            a0 = fmaf(g[sub][c],       th, a0);
            a1 = fmaf(g[sub][64 + c],  th, a1);
            a2 = fmaf(g[sub][128 + c], th, a2);
        }
        *reinterpret_cast<float4*>(gm4 + (size_t)bj * 256 + lane * 4) =
            make_float4(a0, a1, a2, 0.f);
    }
}

// ---------------------------------------------------------------------------
// Main, grid 512 = ((b*64 + io)*4 + jq), 512 thr = 8 waves (16 waves/CU).
// Block = (b, i-OCT, j-quarter of 128). Wave = 16-j chunk x 8 i; lane = co.
// R9 consume structure exactly (1 broadcast b128/pair + 11 VALU/pair, f32
// gm), but each gm dwordx4 is reused across 8 i -> gm L2 stream 134->67 MB
// (the last big modeled term). Pack identical to R9 (i-major, lane-
// contiguous b128 writes). 4 jq blocks combine via atomicAdd into
// prep-zeroed out (commutative adds; ulp-order jitter << threshold).
//   an = a*naf (s folded in pack);  w = relu(al*an + be*a)
//   acc_d += w * (gm_d + r_d*t64)
// ---------------------------------------------------------------------------
__global__ __launch_bounds__(512, 4) void main_kernel(
    const float* __restrict__ adj,     // [1024,512]
    const float* __restrict__ rel,     // [1024,512,3]
    const float* __restrict__ emb,     // [1024,512]
    const float* __restrict__ s_arr,   // [1024]
    const float* __restrict__ gm4,     // [1024,64,4]
    const float* __restrict__ theta,   // [65,64]
    const float* __restrict__ norm_w,  // [65]
    const float* __restrict__ alpha,   // [64]
    const float* __restrict__ beta,    // [64]
    float* __restrict__ out)           // [1024,192]
{
    const int bx   = blockIdx.x;
    const int jq   = bx & 3;
    const int io   = (bx >> 2) & 63;
    const int b    = bx >> 8;
    const int tid  = threadIdx.x;      // 0..511
    const int lane = tid & 63;         // co
    const int wv   = tid >> 6;         // 0..7
    const int bi0  = b * 512 + io * 8;
    const int j0   = jq * 128;

    __shared__ uint4 pk_l[8][128];     // 16 KB, i-major
    __shared__ float red[8][1536];     // 48 KB

    // ---- pack: t = il*128 + j (2 rounds), lane-contiguous b128 writes ----
    {
        const float nw64 = norm_w[64];
        #pragma unroll
        for (int u = 0; u < 2; ++u) {
            int t  = tid + u * 512;        // 0..1023
            int il = t >> 7;               // 0..7
            int j  = t & 127;
            size_t p = (size_t)(bi0 + il) * 512 + j0 + j;
            const float* rp = rel + p * 3;
            float r0 = rp[0], r1 = rp[1], r2 = rp[2];
            float a   = adj[p];
            float naf = s_arr[b * 512 + j0 + j]
                      + nw64 * sqrtf(r0 * r0 + r1 * r1 + r2 * r2) + emb[p];
            uint4 q;
            q.x = __builtin_bit_cast(u32, a * naf);
            q.y = __builtin_bit_cast(u32, a);
            q.z = bf16b(r0) | (bf16b(r1) << 16);
            q.w = bf16b(r2) << 16;
            pk_l[il][j] = q;
        }
    }
    __syncthreads();

    const float al  = alpha[lane];
    const float be  = beta[lane];
    const float t64 = theta[64 * 64 + lane];

    const float4* gmv =
        (const float4*)gm4 + ((size_t)(b * 512 + j0 + wv * 16)) * 64 + lane;

    float acc[8][3];
    #pragma unroll
    for (int il = 0; il < 8; ++il)
        acc[il][0] = acc[il][1] = acc[il][2] = 0.f;

    #pragma unroll 4
    for (int jj = 0; jj < 16; ++jj) {
        float4 g = gmv[(size_t)jj * 64];
        #pragma unroll
        for (int il = 0; il < 8; ++il) {
            uint4 q = pk_l[il][wv * 16 + jj];        // broadcast b128 (~5cy)
            float an = __builtin_bit_cast(float, q.x);
            float av = __builtin_bit_cast(float, q.y);
            float r0 = __builtin_bit_cast(float, q.z << 16);
            float r1 = __builtin_bit_cast(float, q.z & 0xFFFF0000u);
            float r2 = __builtin_bit_cast(float, q.w);
            float w  = fmaxf(fmaf(al, an, be * av), 0.f);
            acc[il][0] = fmaf(w, fmaf(r0, t64, g.x), acc[il][0]);
            acc[il][1] = fmaf(w, fmaf(r1, t64, g.y), acc[il][1]);
            acc[il][2] = fmaf(w, fmaf(r2, t64, g.z), acc[il][2]);
        }
    }

    // ---- 8-wave reduce (lane-contiguous b32, conflict-free) ----
    float* rw = &red[wv][lane];
    #pragma unroll
    for (int il = 0; il < 8; ++il) {
        rw[il * 192]       = acc[il][0];
        rw[il * 192 + 64]  = acc[il][1];
        rw[il * 192 + 128] = acc[il][2];
    }
    __syncthreads();

    #pragma unroll
    for (int k = tid; k < 1536; k += 512) {
        float v = 0.f;
        #pragma unroll
        for (int w8 = 0; w8 < 8; ++w8) v += red[w8][k];
        int il = k / 192, r = k - il * 192;
        atomicAdd(&out[(size_t)(bi0 + il) * 192 + r], v);
    }
}

extern "C" void kernel_launch(void* const* d_in, const int* in_sizes, int n_in,
                              void* d_out, int out_size, void* d_ws, size_t ws_size,
                              hipStream_t stream) {
    const float* geom   = (const float*)d_in[0];
    const float* adj    = (const float*)d_in[1];
    const float* rel    = (const float*)d_in[2];
    const float* emb    = (const float*)d_in[3];
    const float* theta  = (const float*)d_in[4];
    const float* norm_w = (const float*)d_in[5];
    const float* norm_b = (const float*)d_in[6];
    const float* alpha  = (const float*)d_in[7];
    const float* beta   = (const float*)d_in[8];
    float* out = (float*)d_out;

    float* ws  = (float*)d_ws;
    float* s   = ws + WS_S;
    float* gm4 = ws + WS_GM4;

    prep_kernel<<<512, 256, 0, stream>>>(geom, theta, norm_w, norm_b, s, gm4, out);
    main_kernel<<<512, 512, 0, stream>>>(adj, rel, emb, s, gm4, theta, norm_w,
                                         alpha, beta, out);
}

// Round 15
// 21.984 us; speedup vs baseline: 1.2182x; 1.0964x over previous
//
#include <hip/hip_runtime.h>
#include <math.h>

// B=2, N=512, DIM=3, C_IN=64, C_OUT=64
// ws layout (floats): s[1024] | gm8[1024*128 (uint2 per co)]
#define WS_S   0
#define WS_GM8 1024

typedef unsigned int u32;

static __device__ __forceinline__ u32 bf16b(float x) {
    u32 u = __builtin_bit_cast(u32, x);
    return (u + 0x7FFFu + ((u >> 16) & 1u)) >> 16;   // RNE to bf16
}
static __device__ __forceinline__ float blo(u32 b) {   // low bf16 -> f32
    return __builtin_bit_cast(float, b << 16);
}
static __device__ __forceinline__ float bhi(u32 b) {   // high bf16 -> f32
    return __builtin_bit_cast(float, b & 0xFFFF0000u);
}

// ---------------------------------------------------------------------------
// Prep, grid 512 x 256 (R9 structure; gm stored bf16x3 in 8B):
//  all bx:  zero out[bx*384 .. +384)
//  bx<256:  4 bj each:  s[bj] = sum_c ||geom[bj,:,c]||*norm_w[c] + norm_b
//           gm8[bj][co] = uint2{ bf16(a0)|bf16(a1)<<16, bf16(a2)<<16 }
// ---------------------------------------------------------------------------
__global__ __launch_bounds__(256) void prep_kernel(
    const float* __restrict__ geom,    // [1024,3,64]
    const float* __restrict__ theta,   // [65,64]
    const float* __restrict__ norm_w,  // [65]
    const float* __restrict__ norm_b,  // [1]
    float* __restrict__ s,             // [1024]
    uint2* __restrict__ gm8,           // [1024,64]
    float* __restrict__ out)           // [1024,192]
{
    const int bx  = blockIdx.x;
    const int tid = threadIdx.x;

    for (int k = tid; k < 384; k += 256)
        out[(size_t)bx * 384 + k] = 0.f;

    if (bx < 256) {
        const int sub  = tid >> 6;      // which of 4 bj
        const int lane = tid & 63;      // = c, and = co
        const int bj   = bx * 4 + sub;
        __shared__ float g[4][192];     // [d*64 + c]
        const float* gb = geom + (size_t)bj * 192;
        g[sub][lane]       = gb[lane];
        g[sub][lane + 64]  = gb[lane + 64];
        g[sub][lane + 128] = gb[lane + 128];
        __syncthreads();

        {
            float g0 = g[sub][lane], g1 = g[sub][64 + lane], g2 = g[sub][128 + lane];
            float t = sqrtf(g0 * g0 + g1 * g1 + g2 * g2) * norm_w[lane];
            for (int off = 32; off > 0; off >>= 1) t += __shfl_down(t, off);
            if (lane == 0) s[bj] = t + norm_b[0];
        }

        float a0 = 0.f, a1 = 0.f, a2 = 0.f;
        for (int c = 0; c < 64; ++c) {
            float th = theta[c * 64 + lane];
            a0 = fmaf(g[sub][c],       th, a0);
            a1 = fmaf(g[sub][64 + c],  th, a1);
            a2 = fmaf(g[sub][128 + c], th, a2);
        }
        uint2 w;
        w.x = bf16b(a0) | (bf16b(a1) << 16);
        w.y = bf16b(a2) << 16;
        gm8[(size_t)bj * 64 + lane] = w;
    }
}

// ---------------------------------------------------------------------------
// Main, grid 512 = (b*256 + iq*2 + jh), 512 thr = 8 waves (16 waves/CU).
// EXACT R9 structure (best: 22.6us); only change: gm read as 8B uint2
// (bf16x3) instead of 16B float4 -> gm L2 stream 134 -> 67 MB. Unpack ~3
// ops per jj amortized over 4 pairs. Everything else identical.
//   an = a*naf (s folded in pack);  w = relu(al*an + be*a)
//   acc_d += w * (gm_d + r_d*t64)
// ---------------------------------------------------------------------------
__global__ __launch_bounds__(512) void main_kernel(
    const float* __restrict__ adj,     // [1024,512]
    const float* __restrict__ rel,     // [1024,512,3]
    const float* __restrict__ emb,     // [1024,512]
    const float* __restrict__ s_arr,   // [1024]
    const uint2* __restrict__ gm8,     // [1024,64]
    const float* __restrict__ theta,   // [65,64]
    const float* __restrict__ norm_w,  // [65]
    const float* __restrict__ alpha,   // [64]
    const float* __restrict__ beta,    // [64]
    float* __restrict__ out)           // [1024,192]
{
    const int bx   = blockIdx.x;
    const int jh   = bx & 1;
    const int iq   = (bx >> 1) & 127;
    const int b    = bx >> 8;
    const int tid  = threadIdx.x;      // 0..511
    const int lane = tid & 63;         // co
    const int wv   = tid >> 6;         // 0..7
    const int bi0  = b * 512 + iq * 4;
    const int j0   = jh * 256;

    __shared__ uint4 pk_l[4][256];     // 16 KB, i-major
    __shared__ float red[8][768];      // 24 KB

    // ---- pack: t = il*256 + j, lane-contiguous b128 writes (R9) ----
    {
        const float nw64 = norm_w[64];
        #pragma unroll
        for (int u = 0; u < 2; ++u) {
            int t  = tid + u * 512;        // 0..1023
            int il = t >> 8;               // 0..3
            int j  = t & 255;
            size_t p = (size_t)(bi0 + il) * 512 + j0 + j;
            const float* rp = rel + p * 3;
            float r0 = rp[0], r1 = rp[1], r2 = rp[2];
            float a   = adj[p];
            float naf = s_arr[b * 512 + j0 + j]
                      + nw64 * sqrtf(r0 * r0 + r1 * r1 + r2 * r2) + emb[p];
            uint4 q;
            q.x = __builtin_bit_cast(u32, a * naf);
            q.y = __builtin_bit_cast(u32, a);
            q.z = bf16b(r0) | (bf16b(r1) << 16);
            q.w = bf16b(r2) << 16;
            pk_l[il][j] = q;
        }
    }
    __syncthreads();

    const float al  = alpha[lane];
    const float be  = beta[lane];
    const float t64 = theta[64 * 64 + lane];

    const uint2* gmv = gm8 + (size_t)(b * 512 + j0 + wv * 32) * 64 + lane;

    float acc[4][3];
    #pragma unroll
    for (int il = 0; il < 4; ++il)
        acc[il][0] = acc[il][1] = acc[il][2] = 0.f;

    #pragma unroll 4
    for (int jj = 0; jj < 32; ++jj) {
        uint2 gw = gmv[(size_t)jj * 64];           // 8B coalesced
        float gx = blo(gw.x), gy = bhi(gw.x), gz = bhi(gw.y);
        #pragma unroll
        for (int il = 0; il < 4; ++il) {
            uint4 q = pk_l[il][wv * 32 + jj];      // broadcast b128
            float an = __builtin_bit_cast(float, q.x);
            float av = __builtin_bit_cast(float, q.y);
            float r0 = __builtin_bit_cast(float, q.z << 16);
            float r1 = __builtin_bit_cast(float, q.z & 0xFFFF0000u);
            float r2 = __builtin_bit_cast(float, q.w);
            float w  = fmaxf(fmaf(al, an, be * av), 0.f);
            acc[il][0] = fmaf(w, fmaf(r0, t64, gx), acc[il][0]);
            acc[il][1] = fmaf(w, fmaf(r1, t64, gy), acc[il][1]);
            acc[il][2] = fmaf(w, fmaf(r2, t64, gz), acc[il][2]);
        }
    }

    // ---- 8-wave reduce (lane-contiguous b32, conflict-free) ----
    float* rw = &red[wv][lane];
    #pragma unroll
    for (int il = 0; il < 4; ++il) {
        rw[il * 192]       = acc[il][0];
        rw[il * 192 + 64]  = acc[il][1];
        rw[il * 192 + 128] = acc[il][2];
    }
    __syncthreads();

    for (int k = tid; k < 768; k += 512) {
        float v = 0.f;
        #pragma unroll
        for (int w8 = 0; w8 < 8; ++w8) v += red[w8][k];
        int il = k / 192, r = k - il * 192;
        atomicAdd(&out[(size_t)(bi0 + il) * 192 + r], v);
    }
}

extern "C" void kernel_launch(void* const* d_in, const int* in_sizes, int n_in,
                              void* d_out, int out_size, void* d_ws, size_t ws_size,
                              hipStream_t stream) {
    const float* geom   = (const float*)d_in[0];
    const float* adj    = (const float*)d_in[1];
    const float* rel    = (const float*)d_in[2];
    const float* emb    = (const float*)d_in[3];
    const float* theta  = (const float*)d_in[4];
    const float* norm_w = (const float*)d_in[5];
    const float* norm_b = (const float*)d_in[6];
    const float* alpha  = (const float*)d_in[7];
    const float* beta   = (const float*)d_in[8];
    float* out = (float*)d_out;

    float* ws  = (float*)d_ws;
    float* s   = ws + WS_S;
    uint2* gm8 = (uint2*)(ws + WS_GM8);

    prep_kernel<<<512, 256, 0, stream>>>(geom, theta, norm_w, norm_b, s, gm8, out);
    main_kernel<<<512, 512, 0, stream>>>(adj, rel, emb, s, gm8, theta, norm_w,
                                         alpha, beta, out);
}

// Round 16
// 21.771 us; speedup vs baseline: 1.2301x; 1.0098x over previous
//
#include <hip/hip_runtime.h>
#include <math.h>

// B=2, N=512, DIM=3, C_IN=64, C_OUT=64
// ws layout (floats): s[1024] | gm8[1024*128 (uint2 per co)]
#define WS_S   0
#define WS_GM8 1024

typedef unsigned int u32;
typedef float f32x2 __attribute__((ext_vector_type(2)));

static __device__ __forceinline__ u32 bf16b(float x) {
    u32 u = __builtin_bit_cast(u32, x);
    return (u + 0x7FFFu + ((u >> 16) & 1u)) >> 16;   // RNE to bf16
}
static __device__ __forceinline__ float blo(u32 b) {   // low bf16 -> f32
    return __builtin_bit_cast(float, b << 16);
}
static __device__ __forceinline__ float bhi(u32 b) {   // high bf16 -> f32
    return __builtin_bit_cast(float, b & 0xFFFF0000u);
}

// ---------------------------------------------------------------------------
// Prep, grid 512 x 256 (R15, unchanged):
//  all bx:  zero out[bx*384 .. +384)
//  bx<256:  4 bj each:  s[bj] = sum_c ||geom[bj,:,c]||*norm_w[c] + norm_b
//           gm8[bj][co] = uint2{ bf16(a0)|bf16(a1)<<16, bf16(a2)<<16 }
// ---------------------------------------------------------------------------
__global__ __launch_bounds__(256) void prep_kernel(
    const float* __restrict__ geom,    // [1024,3,64]
    const float* __restrict__ theta,   // [65,64]
    const float* __restrict__ norm_w,  // [65]
    const float* __restrict__ norm_b,  // [1]
    float* __restrict__ s,             // [1024]
    uint2* __restrict__ gm8,           // [1024,64]
    float* __restrict__ out)           // [1024,192]
{
    const int bx  = blockIdx.x;
    const int tid = threadIdx.x;

    for (int k = tid; k < 384; k += 256)
        out[(size_t)bx * 384 + k] = 0.f;

    if (bx < 256) {
        const int sub  = tid >> 6;      // which of 4 bj
        const int lane = tid & 63;      // = c, and = co
        const int bj   = bx * 4 + sub;
        __shared__ float g[4][192];     // [d*64 + c]
        const float* gb = geom + (size_t)bj * 192;
        g[sub][lane]       = gb[lane];
        g[sub][lane + 64]  = gb[lane + 64];
        g[sub][lane + 128] = gb[lane + 128];
        __syncthreads();

        {
            float g0 = g[sub][lane], g1 = g[sub][64 + lane], g2 = g[sub][128 + lane];
            float t = sqrtf(g0 * g0 + g1 * g1 + g2 * g2) * norm_w[lane];
            for (int off = 32; off > 0; off >>= 1) t += __shfl_down(t, off);
            if (lane == 0) s[bj] = t + norm_b[0];
        }

        float a0 = 0.f, a1 = 0.f, a2 = 0.f;
        for (int c = 0; c < 64; ++c) {
            float th = theta[c * 64 + lane];
            a0 = fmaf(g[sub][c],       th, a0);
            a1 = fmaf(g[sub][64 + c],  th, a1);
            a2 = fmaf(g[sub][128 + c], th, a2);
        }
        uint2 w;
        w.x = bf16b(a0) | (bf16b(a1) << 16);
        w.y = bf16b(a2) << 16;
        gm8[(size_t)bj * 64 + lane] = w;
    }
}

// ---------------------------------------------------------------------------
// Main, grid 512 = (b*256 + iq*2 + jh), 512 thr = 8 waves (16 waves/CU).
// R15 structure exactly; only change: (d0,d1) accumulation via packed-f32
// vector fma (v_pk_fma_f32) -> 11 -> 9 VALU issue slots per pair.
//   an = a*naf (s folded in pack);  w = relu(al*an + be*a)
//   acc_d += w * (gm_d + r_d*t64)
// ---------------------------------------------------------------------------
__global__ __launch_bounds__(512) void main_kernel(
    const float* __restrict__ adj,     // [1024,512]
    const float* __restrict__ rel,     // [1024,512,3]
    const float* __restrict__ emb,     // [1024,512]
    const float* __restrict__ s_arr,   // [1024]
    const uint2* __restrict__ gm8,     // [1024,64]
    const float* __restrict__ theta,   // [65,64]
    const float* __restrict__ norm_w,  // [65]
    const float* __restrict__ alpha,   // [64]
    const float* __restrict__ beta,    // [64]
    float* __restrict__ out)           // [1024,192]
{
    const int bx   = blockIdx.x;
    const int jh   = bx & 1;
    const int iq   = (bx >> 1) & 127;
    const int b    = bx >> 8;
    const int tid  = threadIdx.x;      // 0..511
    const int lane = tid & 63;         // co
    const int wv   = tid >> 6;         // 0..7
    const int bi0  = b * 512 + iq * 4;
    const int j0   = jh * 256;

    __shared__ uint4 pk_l[4][256];     // 16 KB, i-major
    __shared__ float red[8][768];      // 24 KB

    // ---- pack: t = il*256 + j, lane-contiguous b128 writes (R9) ----
    {
        const float nw64 = norm_w[64];
        #pragma unroll
        for (int u = 0; u < 2; ++u) {
            int t  = tid + u * 512;        // 0..1023
            int il = t >> 8;               // 0..3
            int j  = t & 255;
            size_t p = (size_t)(bi0 + il) * 512 + j0 + j;
            const float* rp = rel + p * 3;
            float r0 = rp[0], r1 = rp[1], r2 = rp[2];
            float a   = adj[p];
            float naf = s_arr[b * 512 + j0 + j]
                      + nw64 * sqrtf(r0 * r0 + r1 * r1 + r2 * r2) + emb[p];
            uint4 q;
            q.x = __builtin_bit_cast(u32, a * naf);
            q.y = __builtin_bit_cast(u32, a);
            q.z = bf16b(r0) | (bf16b(r1) << 16);
            q.w = bf16b(r2) << 16;
            pk_l[il][j] = q;
        }
    }
    __syncthreads();

    const float al  = alpha[lane];
    const float be  = beta[lane];
    const float t64 = theta[64 * 64 + lane];
    const f32x2 t64v = {t64, t64};

    const uint2* gmv = gm8 + (size_t)(b * 512 + j0 + wv * 32) * 64 + lane;

    f32x2 acc01[4];
    float acc2[4];
    #pragma unroll
    for (int il = 0; il < 4; ++il) { acc01[il] = (f32x2){0.f, 0.f}; acc2[il] = 0.f; }

    #pragma unroll 4
    for (int jj = 0; jj < 32; ++jj) {
        uint2 gw = gmv[(size_t)jj * 64];           // 8B coalesced
        const f32x2 g01 = {blo(gw.x), bhi(gw.x)};
        const float gz  = bhi(gw.y);
        #pragma unroll
        for (int il = 0; il < 4; ++il) {
            uint4 q = pk_l[il][wv * 32 + jj];      // broadcast b128
            float an = __builtin_bit_cast(float, q.x);
            float av = __builtin_bit_cast(float, q.y);
            f32x2 r01 = {blo(q.z), bhi(q.z)};
            float r2  = __builtin_bit_cast(float, q.w);
            float w  = fmaxf(fmaf(al, an, be * av), 0.f);
            f32x2 wv2 = {w, w};
            f32x2 t01 = __builtin_elementwise_fma(r01, t64v, g01);  // v_pk_fma
            acc01[il] = __builtin_elementwise_fma(wv2, t01, acc01[il]);
            acc2[il]  = fmaf(w, fmaf(r2, t64, gz), acc2[il]);
        }
    }

    // ---- 8-wave reduce (lane-contiguous b32, conflict-free) ----
    float* rw = &red[wv][lane];
    #pragma unroll
    for (int il = 0; il < 4; ++il) {
        rw[il * 192]       = acc01[il].x;
        rw[il * 192 + 64]  = acc01[il].y;
        rw[il * 192 + 128] = acc2[il];
    }
    __syncthreads();

    for (int k = tid; k < 768; k += 512) {
        float v = 0.f;
        #pragma unroll
        for (int w8 = 0; w8 < 8; ++w8) v += red[w8][k];
        int il = k / 192, r = k - il * 192;
        atomicAdd(&out[(size_t)(bi0 + il) * 192 + r], v);
    }
}

extern "C" void kernel_launch(void* const* d_in, const int* in_sizes, int n_in,
                              void* d_out, int out_size, void* d_ws, size_t ws_size,
                              hipStream_t stream) {
    const float* geom   = (const float*)d_in[0];
    const float* adj    = (const float*)d_in[1];
    const float* rel    = (const float*)d_in[2];
    const float* emb    = (const float*)d_in[3];
    const float* theta  = (const float*)d_in[4];
    const float* norm_w = (const float*)d_in[5];
    const float* norm_b = (const float*)d_in[6];
    const float* alpha  = (const float*)d_in[7];
    const float* beta   = (const float*)d_in[8];
    float* out = (float*)d_out;

    float* ws  = (float*)d_ws;
    float* s   = ws + WS_S;
    uint2* gm8 = (uint2*)(ws + WS_GM8);

    prep_kernel<<<512, 256, 0, stream>>>(geom, theta, norm_w, norm_b, s, gm8, out);
    main_kernel<<<512, 512, 0, stream>>>(adj, rel, emb, s, gm8, theta, norm_w,
                                         alpha, beta, out);
}